// Round 4
// baseline (106.007 us; speedup 1.0000x reference)
//
#include <hip/hip_runtime.h>

typedef __bf16 bf16x8 __attribute__((ext_vector_type(8)));
typedef float f32x4 __attribute__((ext_vector_type(4)));

// Problem constants
#define BB 4
#define CC 64
#define OO 64
#define HH 128
#define WW 128

// ---------------------------------------------------------------------------
// Kernel 1: weight prepack only (tiny node, ~1 us). MFMA A-frag order, bf16.
// t = (i*3+j)*2 + ch, c = ch*32 + (l>>4)*8 + jj, o = og*16 + (l&15).
// aw16[(((og*18)+t)*64 + l)*8 + jj]
// ---------------------------------------------------------------------------
__global__ __launch_bounds__(256) void prepack_kernel(
    const float* __restrict__ w, unsigned short* __restrict__ aw)
{
    int gid = blockIdx.x * 256 + threadIdx.x;   // 0..4607
    if (gid >= 4608) return;
    int og  = gid / 1152;
    int rem = gid - og * 1152;
    int t = rem >> 6;
    int l = rem & 63;
    int q = l >> 4;
    int m = l & 15;
    int o  = og * 16 + m;
    int ij = t >> 1;
    int ch = t & 1;
    int i = ij / 3;
    int j = ij - i * 3;
    union { unsigned short u[8]; uint4 v; } pk;
#pragma unroll
    for (int jj = 0; jj < 8; ++jj) {
        int c = ch * 32 + q * 8 + jj;
        float wf = w[((o * CC + c) * 3 + i) * 3 + j];
        __bf16 h = (__bf16)wf;
        pk.u[jj] = __builtin_bit_cast(unsigned short, h);
    }
    ((uint4*)aw)[gid] = pk.v;
}

// ---------------------------------------------------------------------------
// Kernel 2: FUSED prescale + conv. One block per (b, y): 64 o x 128 x out.
//
// Staging: 12 chunks (3 rows x 4 x-chunks of 32). Per chunk:
//   A: coalesced fp32 reads of in[b][c][yy][x0..x0+31], scaled by f(alpha),
//      into trans[c][x] (stride 33 -> 2-way bank aliasing, free per m136).
//   B: transpose-read 8 channels, pack bf16x8, one ds_write_b128 into
//      tile[(r*130+xt)*72 + cg*8]  (quad residues (xw+cg)%8 uniform -> balanced).
// Edge columns xt=0,129 zeroed once (halo). OOB rows produce zeros via v=0.
// Input rows are re-read by 3 neighboring blocks; XCD swizzle makes that
// reuse temporally adjacent -> L2 hit, HBM fetch ~ one pass.
//
// Compute: 4 waves, 2x4 mfma_f32_16x16x32_bf16 acc, identical to round-3.
// LDS: 56160 (tile) + 8448 (trans) = 64608 B -> 2 blocks/CU.
// ---------------------------------------------------------------------------
__global__ __launch_bounds__(256, 2) void fused_conv_kernel(
    const float* __restrict__ in, const float* __restrict__ alpha,
    const unsigned short* __restrict__ aw, const float* __restrict__ bias,
    const float* __restrict__ pa, const float* __restrict__ pb, const float* __restrict__ pc,
    float* __restrict__ out)
{
    __shared__ unsigned short tile[3 * 130 * 72];   // 56,160 B
    __shared__ float trans[64][33];                 //  8,448 B

    // XCD swizzle: xcd = bid&7 -> one (b, y-half) slab per XCD
    int n   = blockIdx.x;             // 0..511
    int xcd = n & 7;
    int idx = n >> 3;                 // 0..63
    int b   = xcd >> 1;
    int y   = (xcd & 1) * 64 + idx;
    int tid = threadIdx.x;

    float A  = *pa, Bc = *pb, Cc = *pc;

    // zero halo columns xt=0 and xt=129 (48 x 16B chunks)
    if (tid < 48) {
        int g = tid & 7;            // 8 chunks cover c=0..63
        int e = (tid >> 3) & 1;
        int r = tid >> 4;           // 0..2
        int xt = e ? 129 : 0;
        *(uint4*)(tile + (r * 130 + xt) * 72 + g * 8) = make_uint4(0u, 0u, 0u, 0u);
    }

    int xA = tid & 31, c8 = tid >> 5;   // phase A role
    int xw = tid >> 3, cg = tid & 7;    // phase B role

#pragma unroll
    for (int r = 0; r < 3; ++r) {
        int yy = y + r - 1;
        bool inr = (0 <= yy) && (yy < HH);
#pragma unroll
        for (int xc = 0; xc < 4; ++xc) {
            int x0 = xc * 32;
            // phase A: coalesced scaled reads -> trans
            float av = inr ? alpha[(b * HH + yy) * WW + x0 + xA] : 0.f;
            float f  = (A * av + Bc) * av + Cc;
#pragma unroll
            for (int k = 0; k < 8; ++k) {
                int c = c8 * 8 + k;
                float v = inr ? in[((b * CC + c) * HH + yy) * WW + x0 + xA] : 0.f;
                trans[c][xA] = v * f;
            }
            __syncthreads();
            // phase B: transpose + bf16 pack -> tile (channel-innermost)
            union { unsigned short u[8]; uint4 v; } pk;
#pragma unroll
            for (int k = 0; k < 8; ++k) {
                __bf16 h = (__bf16)trans[cg * 8 + k][xw];
                pk.u[k] = __builtin_bit_cast(unsigned short, h);
            }
            int xt = x0 + xw + 1;
            *(uint4*)(tile + (r * 130 + xt) * 72 + cg * 8) = pk.v;
            __syncthreads();
        }
    }
    // last __syncthreads() above also orders the tid<48 halo zeroing

    int wv = tid >> 6;
    int l  = tid & 63;
    int oh = wv & 1;    // o-half
    int nh = wv >> 1;   // x-half
    int q  = l >> 4;
    int m  = l & 15;

    f32x4 acc[2][4];
#pragma unroll
    for (int ag = 0; ag < 2; ++ag)
#pragma unroll
        for (int nf = 0; nf < 4; ++nf)
            acc[ag][nf] = (f32x4){0.f, 0.f, 0.f, 0.f};

    const uint4* awv = (const uint4*)aw + (size_t)(oh * 2) * 18 * 64 + l;

#pragma unroll 3
    for (int ij = 0; ij < 9; ++ij) {
        const int i = ij / 3;
        const int j = ij - i * 3;
#pragma unroll
        for (int ch = 0; ch < 2; ++ch) {
            const int t = ij * 2 + ch;
            bf16x8 afrag[2], bfrag[4];
#pragma unroll
            for (int ag = 0; ag < 2; ++ag)
                afrag[ag] = __builtin_bit_cast(bf16x8, awv[(ag * 18 + t) * 64]);
#pragma unroll
            for (int nf = 0; nf < 4; ++nf) {
                int xt = nh * 64 + nf * 16 + m + j;   // input x = xt-1 = xout + j - 1
                bfrag[nf] = __builtin_bit_cast(bf16x8,
                    *(const uint4*)(tile + (i * 130 + xt) * 72 + ch * 32 + q * 8));
            }
#pragma unroll
            for (int ag = 0; ag < 2; ++ag)
#pragma unroll
                for (int nf = 0; nf < 4; ++nf)
                    acc[ag][nf] = __builtin_amdgcn_mfma_f32_16x16x32_bf16(
                        afrag[ag], bfrag[nf], acc[ag][nf], 0, 0, 0);
        }
    }

    // epilogue: D layout (m89): o = q*4 + r, x = lane&15
#pragma unroll
    for (int ag = 0; ag < 2; ++ag) {
#pragma unroll
        for (int r = 0; r < 4; ++r) {
            int o = (oh * 2 + ag) * 16 + q * 4 + r;
            float bv = bias[o];
#pragma unroll
            for (int nf = 0; nf < 4; ++nf) {
                int x = nh * 64 + nf * 16 + m;
                out[((size_t)(b * OO + o) * HH + y) * WW + x] = acc[ag][nf][r] + bv;
            }
        }
    }
}

// ---------------------------------------------------------------------------
extern "C" void kernel_launch(void* const* d_in, const int* in_sizes, int n_in,
                              void* d_out, int out_size, void* d_ws, size_t ws_size,
                              hipStream_t stream) {
    const float* inputs = (const float*)d_in[0];
    const float* alpha  = (const float*)d_in[1];
    const float* weight = (const float*)d_in[2];
    const float* bias   = (const float*)d_in[3];
    const float* pa     = (const float*)d_in[4];
    const float* pb     = (const float*)d_in[5];
    const float* pc     = (const float*)d_in[6];
    float* out = (float*)d_out;

    unsigned short* aw = (unsigned short*)d_ws;    // 73,728 B prepacked weights

    prepack_kernel<<<18, 256, 0, stream>>>(weight, aw);
    fused_conv_kernel<<<BB * HH, 256, 0, stream>>>(inputs, alpha, aw, bias,
                                                   pa, pb, pc, out);
}